// Round 11
// baseline (257.917 us; speedup 1.0000x reference)
//
#include <hip/hip_runtime.h>
#include <stdint.h>

#define NS 65536      // B*H*W samples
#define D 64          // embed dim
#define K 1024        // codebook size
#define NEL 4194304   // NS*D
#define MARGIN 0.05f  // approx-dist uncertainty margin (>> 2*eps ~ 1.4e-3)

typedef short bf16x8 __attribute__((ext_vector_type(8)));
typedef float f32x4 __attribute__((ext_vector_type(4)));

static __device__ __forceinline__ unsigned short bf16_rne(float x) {
    union { float f; uint32_t u; } v; v.f = x;
    uint32_t r = v.u + 0x7FFFu + ((v.u >> 16) & 1u);
    return (unsigned short)(r >> 16);
}
static __device__ __forceinline__ float bf16f(unsigned short h) {
    union { uint32_t u; float f; } v; v.u = ((uint32_t)h) << 16;
    return v.f;
}

// ---------------------------------------------------------------------------
// Prep: split codebook into bf16 hi/lo [K][D] row-major (MFMA-B-ready),
// compute ||m_k||^2 in fp32, zero the loss accumulator.
// ---------------------------------------------------------------------------
__global__ __launch_bounds__(256) void vq_prep(
    const float* __restrict__ cm,        // [D,K]
    unsigned short* __restrict__ mhi,    // [K,D] bf16 bits
    unsigned short* __restrict__ mlo,    // [K,D] bf16 bits
    float* __restrict__ cnorm,           // [K]
    double* __restrict__ acc)
{
    const int tx = threadIdx.x;
    const int kl = tx & 63, dq = tx >> 6;
    const int k = blockIdx.x * 64 + kl;
    if (blockIdx.x == 0 && tx == 0) *acc = 0.0;

    unsigned short h[16], lo[16];
    float p = 0.f;
#pragma unroll
    for (int j = 0; j < 16; ++j) {
        float v = cm[(dq*16 + j) * K + k];   // coalesced across k
        unsigned short hb = bf16_rne(v);
        h[j] = hb;
        lo[j] = bf16_rne(v - bf16f(hb));
        p = fmaf(v, v, p);
    }
    bf16x8 v0, v1, w0, w1;
#pragma unroll
    for (int j = 0; j < 8; ++j) {
        v0[j] = (short)h[j];  v1[j] = (short)h[8+j];
        w0[j] = (short)lo[j]; w1[j] = (short)lo[8+j];
    }
    *(bf16x8*)(mhi + (size_t)k*D + dq*16)     = v0;
    *(bf16x8*)(mhi + (size_t)k*D + dq*16 + 8) = v1;
    *(bf16x8*)(mlo + (size_t)k*D + dq*16)     = w0;
    *(bf16x8*)(mlo + (size_t)k*D + dq*16 + 8) = w1;

    __shared__ float pn[4][64];
    pn[dq][kl] = p;
    __syncthreads();
    if (tx < 64)
        cnorm[blockIdx.x*64 + tx] = (pn[0][tx]+pn[1][tx]) + (pn[2][tx]+pn[3][tx]);
}

// ---------------------------------------------------------------------------
// Main: MFMA bf16-split distance GEMM. 2048 blocks x 256 thr (4 waves).
// R10 vs R9: 32 samples/block; wave w = (code-half ch = w>>1) x (sample-half
// sh = w&1): 16 samples x 512 codes in 32 iters of 16 codes. Doubles offered
// blocks/CU (grid was the limiter: occupancy 42%, VGPR 40, both pipes idle).
// dot = x_hi.m_hi + x_hi.m_lo + x_lo.m_hi; per-lane top-2; LDS merge across
// 16 lanes x 2 code-halves; margin cases rescored exactly in fp32 from cm.
// A-frag: A[m=lane&15][k=quad*8+j]; C/D: col(code)=lane&15,
// row(sample)=quad*4+reg  [guide §3, m89/m120 verified].
// ---------------------------------------------------------------------------
__global__ __launch_bounds__(256, 8) void vq_main(
    const float* __restrict__ xin,           // [NS,D]
    const float* __restrict__ cm,            // [D,K] (exact rescore)
    const unsigned short* __restrict__ mhi,  // [K,D]
    const unsigned short* __restrict__ mlo,  // [K,D]
    const float* __restrict__ cnorm,         // [K]
    float* __restrict__ outq,                // [NS,D]
    float* __restrict__ outidx,              // [NS]
    double* __restrict__ acc_g)
{
    // phase1: xh[32][72] + xl[32][72] bf16 (9216 B)
    // phase2 (alias): mb1/mb2 f32[1024] + mi1/mi2 i16[1024] (12288 B)
    // phase3 (alias): red f32[256]
    __shared__ char smem[12288];
    __shared__ float cn_lds[1024];
    __shared__ int   widx[32];

    unsigned short* xh = (unsigned short*)smem;           // stride 72
    unsigned short* xl = (unsigned short*)(smem + 4608);
    float* mb1 = (float*)smem;
    float* mb2 = (float*)(smem + 4096);
    short* mi1 = (short*)(smem + 8192);
    short* mi2 = (short*)(smem + 10240);
    float* red = (float*)smem;

    const int tx = threadIdx.x;
    const int S0 = blockIdx.x * 32;

    // ---- stage x -> bf16 hi/lo in LDS ----
    {
        const int s = tx >> 3, d0 = (tx & 7) * 8;   // sample 0..31, 8 dims
        const float* gp = xin + (size_t)(S0 + s) * D + d0;
        float4 a = ((const float4*)gp)[0];
        float4 b = ((const float4*)gp)[1];
        float vv[8] = {a.x, a.y, a.z, a.w, b.x, b.y, b.z, b.w};
        bf16x8 hv, lv;
#pragma unroll
        for (int j = 0; j < 8; ++j) {
            unsigned short hb = bf16_rne(vv[j]);
            hv[j] = (short)hb;
            lv[j] = (short)bf16_rne(vv[j] - bf16f(hb));
        }
        *(bf16x8*)(xh + s*72 + d0) = hv;
        *(bf16x8*)(xl + s*72 + d0) = lv;
#pragma unroll
        for (int q = 0; q < 4; ++q) cn_lds[q*256 + tx] = cnorm[q*256 + tx];
    }
    __syncthreads();

    const int w = tx >> 6, l = tx & 63;
    const int quad = l >> 4, col = l & 15;
    const int sh = w & 1;        // sample half
    const int ch = w >> 1;       // code half

    // loop-invariant A fragments: local sample = sh*16 + col, dims quad*8..+8
    const int srow = sh*16 + col;
    bf16x8 ahi0 = *(const bf16x8*)(xh + srow*72 + quad*8);
    bf16x8 ahi1 = *(const bf16x8*)(xh + srow*72 + 32 + quad*8);
    bf16x8 alo0 = *(const bf16x8*)(xl + srow*72 + quad*8);
    bf16x8 alo1 = *(const bf16x8*)(xl + srow*72 + 32 + quad*8);

    float b1[4], b2[4]; int i1[4], i2[4];
#pragma unroll
    for (int r = 0; r < 4; ++r) { b1[r]=3.4e38f; b2[r]=3.4e38f; i1[r]=0; i2[r]=0; }

    // B frags: lane supplies code = ch*512 + kb*16 + col, dims quad*8+j
    const unsigned short* bh = mhi + (size_t)(ch*512 + col)*D + quad*8;
    const unsigned short* bl = mlo + (size_t)(ch*512 + col)*D + quad*8;

    for (int kb = 0; kb < 32; ++kb) {
        bf16x8 bh0 = *(const bf16x8*)(bh);
        bf16x8 bh1 = *(const bf16x8*)(bh + 32);
        bf16x8 bl0 = *(const bf16x8*)(bl);
        bf16x8 bl1 = *(const bf16x8*)(bl + 32);
        f32x4 z = {0.f, 0.f, 0.f, 0.f};
        f32x4 hh = __builtin_amdgcn_mfma_f32_16x16x32_bf16(ahi0, bh0, z, 0,0,0);
        hh       = __builtin_amdgcn_mfma_f32_16x16x32_bf16(ahi1, bh1, hh, 0,0,0);
        f32x4 hl = __builtin_amdgcn_mfma_f32_16x16x32_bf16(ahi0, bl0, z, 0,0,0);
        hl       = __builtin_amdgcn_mfma_f32_16x16x32_bf16(ahi1, bl1, hl, 0,0,0);
        f32x4 lh = __builtin_amdgcn_mfma_f32_16x16x32_bf16(alo0, bh0, z, 0,0,0);
        lh       = __builtin_amdgcn_mfma_f32_16x16x32_bf16(alo1, bh1, lh, 0,0,0);
        const int kcode = ch*512 + kb*16 + col;
        const float cn = cn_lds[kcode];
#pragma unroll
        for (int r = 0; r < 4; ++r) {
            float dot = (hh[r] + hl[r]) + lh[r];
            float d = fmaf(-2.f, dot, cn);
            bool c1 = d < b1[r];
            bool c2 = d < b2[r];
            b2[r] = c1 ? b1[r] : (c2 ? d : b2[r]);
            i2[r] = c1 ? i1[r] : (c2 ? kcode : i2[r]);
            b1[r] = c1 ? d : b1[r];
            i1[r] = c1 ? kcode : i1[r];
        }
        bh += 16*D;
        bl += 16*D;
    }

    // ---- merge per-lane top-2 across 16 lanes x 2 code-halves ----
    __syncthreads();   // xh/xl dead (frags in regs) before alias overwrite
#pragma unroll
    for (int r = 0; r < 4; ++r) {
        mb1[tx*4 + r] = b1[r];
        mb2[tx*4 + r] = b2[r];
        mi1[tx*4 + r] = (short)i1[r];
        mi2[tx*4 + r] = (short)i2[r];
    }
    __syncthreads();

    if (tx < 32) {   // thread tx owns local sample tx
        const int msh = tx >> 4, mq = (tx >> 2) & 3, mr = tx & 3;
        float B1 = 3.4e38f, B2 = 3.4e38f; int I1 = 0, I2 = 0;
#pragma unroll
        for (int mch = 0; mch < 2; ++mch) {
            const int mw = mch*2 + msh;
#pragma unroll
            for (int c = 0; c < 16; ++c) {
                const int e = (mw*64 + mq*16 + c)*4 + mr;
                float v1 = mb1[e]; int j1 = mi1[e];
                float v2 = mb2[e]; int j2 = mi2[e];
                if (v1 < B1)      { B2 = B1; I2 = I1; B1 = v1; I1 = j1; }
                else if (v1 < B2) { B2 = v1; I2 = j1; }
                if (v2 < B1)      { B2 = B1; I2 = I1; B1 = v2; I1 = j2; }
                else if (v2 < B2) { B2 = v2; I2 = j2; }
            }
        }
        int winner = I1;
        if (B2 - B1 < MARGIN) {
            // exact fp32 rescore of both candidates from original cm
            const float* xp = xin + (size_t)(S0 + tx) * D;
            float a0=0,a1=0,a2=0,a3=0, e0=0,e1=0,e2=0,e3=0;
            for (int dd = 0; dd < D; dd += 4) {
                float x0 = xp[dd], x1 = xp[dd+1], x2 = xp[dd+2], x3 = xp[dd+3];
                a0 = fmaf(x0, cm[(dd+0)*K + I1], a0);
                a1 = fmaf(x1, cm[(dd+1)*K + I1], a1);
                a2 = fmaf(x2, cm[(dd+2)*K + I1], a2);
                a3 = fmaf(x3, cm[(dd+3)*K + I1], a3);
                e0 = fmaf(x0, cm[(dd+0)*K + I2], e0);
                e1 = fmaf(x1, cm[(dd+1)*K + I2], e1);
                e2 = fmaf(x2, cm[(dd+2)*K + I2], e2);
                e3 = fmaf(x3, cm[(dd+3)*K + I2], e3);
            }
            float d1 = fmaf(-2.f, (a0+a1)+(a2+a3), cn_lds[I1]);
            float d2 = fmaf(-2.f, (e0+e1)+(e2+e3), cn_lds[I2]);
            if (d2 < d1 || (d2 == d1 && I2 < I1)) winner = I2;
        }
        widx[tx] = winner;
    }
    __syncthreads();

    // ---- gather (hi+lo reconstruct, coalesced) + STE + loss partial ----
    const int sl = tx >> 3, d0 = (tx & 7) * 8;
    const int gs = S0 + sl;
    const int wi = widx[sl];
    bf16x8 h0 = *(const bf16x8*)(mhi + (size_t)wi*D + d0);
    bf16x8 l0 = *(const bf16x8*)(mlo + (size_t)wi*D + d0);
    const float* xr = xin + (size_t)gs*D + d0;
    float* oq = outq + (size_t)gs*D + d0;
    float psum = 0.f;
#pragma unroll
    for (int g = 0; g < 2; ++g) {
        float4 xv = *(const float4*)(xr + 4*g);
        float q0 = bf16f((unsigned short)h0[4*g+0]) + bf16f((unsigned short)l0[4*g+0]);
        float q1 = bf16f((unsigned short)h0[4*g+1]) + bf16f((unsigned short)l0[4*g+1]);
        float q2 = bf16f((unsigned short)h0[4*g+2]) + bf16f((unsigned short)l0[4*g+2]);
        float q3 = bf16f((unsigned short)h0[4*g+3]) + bf16f((unsigned short)l0[4*g+3]);
        float dx = q0 - xv.x, dy = q1 - xv.y, dz = q2 - xv.z, dw = q3 - xv.w;
        float4 o;
        o.x = xv.x + dx; o.y = xv.y + dy; o.z = xv.z + dz; o.w = xv.w + dw;
        *(float4*)(oq + 4*g) = o;
        psum = fmaf(dx, dx, psum);
        psum = fmaf(dy, dy, psum);
        psum = fmaf(dz, dz, psum);
        psum = fmaf(dw, dw, psum);
    }

    if (tx < 32)
        outidx[S0 + tx] = (float)widx[tx];

    red[tx] = psum;
    __syncthreads();
    for (int st = 128; st > 0; st >>= 1) {
        if (tx < st) red[tx] += red[tx + st];
        __syncthreads();
    }
    if (tx == 0) atomicAdd(acc_g, (double)red[0]);
}

// ---------------------------------------------------------------------------
// Finalize: loss = m + 0.25*m where m = mean((q-x)^2)
// ---------------------------------------------------------------------------
__global__ void vq_finalize(const double* __restrict__ acc,
                            float* __restrict__ loss_out)
{
    float m = (float)(*acc / (double)NEL);
    *loss_out = m + 0.25f * m;
}

extern "C" void kernel_launch(void* const* d_in, const int* in_sizes, int n_in,
                              void* d_out, int out_size, void* d_ws, size_t ws_size,
                              hipStream_t stream) {
    const float* xin = (const float*)d_in[0];   // [16,64,64,64] fp32
    const float* cm  = (const float*)d_in[1];   // [64,1024] fp32

    float* out     = (float*)d_out;
    float* outq    = out;                 // 4194304 floats
    float* outidx  = out + NEL;           // 65536 floats (indices)
    float* outloss = out + NEL + NS;      // 1 float

    // workspace: mhi 128 KB | mlo 128 KB | cnorm 4 KB | acc 8 B
    unsigned short* mhi = (unsigned short*)d_ws;
    unsigned short* mlo = mhi + (size_t)K * D;
    float*  cnorm = (float*)((char*)d_ws + 262144);
    double* acc   = (double*)((char*)d_ws + 266240);

    vq_prep<<<16, 256, 0, stream>>>(cm, mhi, mlo, cnorm, acc);
    vq_main<<<2048, 256, 0, stream>>>(xin, cm, mhi, mlo, cnorm, outq, outidx, acc);
    vq_finalize<<<1, 1, 0, stream>>>(acc, outloss);
}

// Round 12
// 236.530 us; speedup vs baseline: 1.0904x; 1.0904x over previous
//
#include <hip/hip_runtime.h>
#include <stdint.h>

#define NS 65536      // B*H*W samples
#define D 64          // embed dim
#define K 1024        // codebook size
#define NEL 4194304   // NS*D
#define MARGIN 0.05f  // approx-dist uncertainty margin (>> 2*eps ~ 1.4e-3)

typedef short bf16x8 __attribute__((ext_vector_type(8)));
typedef float f32x4 __attribute__((ext_vector_type(4)));

static __device__ __forceinline__ unsigned short bf16_rne(float x) {
    union { float f; uint32_t u; } v; v.f = x;
    uint32_t r = v.u + 0x7FFFu + ((v.u >> 16) & 1u);
    return (unsigned short)(r >> 16);
}
static __device__ __forceinline__ float bf16f(unsigned short h) {
    union { uint32_t u; float f; } v; v.u = ((uint32_t)h) << 16;
    return v.f;
}

// ---------------------------------------------------------------------------
// Prep: split codebook into bf16 hi/lo [K][D] row-major (MFMA-B-ready),
// compute ||m_k||^2 in fp32, zero the loss accumulator.
// ---------------------------------------------------------------------------
__global__ __launch_bounds__(256) void vq_prep(
    const float* __restrict__ cm,        // [D,K]
    unsigned short* __restrict__ mhi,    // [K,D] bf16 bits
    unsigned short* __restrict__ mlo,    // [K,D] bf16 bits
    float* __restrict__ cnorm,           // [K]
    double* __restrict__ acc)
{
    const int tx = threadIdx.x;
    const int kl = tx & 63, dq = tx >> 6;
    const int k = blockIdx.x * 64 + kl;
    if (blockIdx.x == 0 && tx == 0) *acc = 0.0;

    unsigned short h[16], lo[16];
    float p = 0.f;
#pragma unroll
    for (int j = 0; j < 16; ++j) {
        float v = cm[(dq*16 + j) * K + k];   // coalesced across k
        unsigned short hb = bf16_rne(v);
        h[j] = hb;
        lo[j] = bf16_rne(v - bf16f(hb));
        p = fmaf(v, v, p);
    }
    bf16x8 v0, v1, w0, w1;
#pragma unroll
    for (int j = 0; j < 8; ++j) {
        v0[j] = (short)h[j];  v1[j] = (short)h[8+j];
        w0[j] = (short)lo[j]; w1[j] = (short)lo[8+j];
    }
    *(bf16x8*)(mhi + (size_t)k*D + dq*16)     = v0;
    *(bf16x8*)(mhi + (size_t)k*D + dq*16 + 8) = v1;
    *(bf16x8*)(mlo + (size_t)k*D + dq*16)     = w0;
    *(bf16x8*)(mlo + (size_t)k*D + dq*16 + 8) = w1;

    __shared__ float pn[4][64];
    pn[dq][kl] = p;
    __syncthreads();
    if (tx < 64)
        cnorm[blockIdx.x*64 + tx] = (pn[0][tx]+pn[1][tx]) + (pn[2][tx]+pn[3][tx]);
}

// ---------------------------------------------------------------------------
// Main: MFMA bf16-split distance GEMM. 2048 blocks x 256 thr (4 waves).
// Wave w = (code-half ch = w>>1) x (sample-half sh = w&1): 16 samples x 512
// codes in 32 iters of 16 codes.
// R11 vs R10: launch_bounds back to (256,4) — R10's (256,8) capped VGPRs at
// 64 < ~60-70 live set and spilled B-frags to scratch (FETCH 11->37 MB,
// WRITE 17->54 MB, 199 µs). With cap 128 and LDS 16.9 KB the HW residency
// is min(9 LDS-blocks, 8 offered, 12 VGPR-waves) = 8 blocks/CU = 32 waves.
// dot = x_hi.m_hi + x_hi.m_lo + x_lo.m_hi; per-lane top-2; LDS merge across
// 16 lanes x 2 code-halves; margin cases rescored exactly in fp32 from cm.
// ---------------------------------------------------------------------------
__global__ __launch_bounds__(256, 4) void vq_main(
    const float* __restrict__ xin,           // [NS,D]
    const float* __restrict__ cm,            // [D,K] (exact rescore)
    const unsigned short* __restrict__ mhi,  // [K,D]
    const unsigned short* __restrict__ mlo,  // [K,D]
    const float* __restrict__ cnorm,         // [K]
    float* __restrict__ outq,                // [NS,D]
    float* __restrict__ outidx,              // [NS]
    double* __restrict__ acc_g)
{
    // phase1: xh[32][72] + xl[32][72] bf16 (9216 B)
    // phase2 (alias): mb1/mb2 f32[1024] + mi1/mi2 i16[1024] (12288 B)
    // phase3 (alias): red f32[256]
    __shared__ char smem[12288];
    __shared__ float cn_lds[1024];
    __shared__ int   widx[32];

    unsigned short* xh = (unsigned short*)smem;           // stride 72
    unsigned short* xl = (unsigned short*)(smem + 4608);
    float* mb1 = (float*)smem;
    float* mb2 = (float*)(smem + 4096);
    short* mi1 = (short*)(smem + 8192);
    short* mi2 = (short*)(smem + 10240);
    float* red = (float*)smem;

    const int tx = threadIdx.x;
    const int S0 = blockIdx.x * 32;

    // ---- stage x -> bf16 hi/lo in LDS ----
    {
        const int s = tx >> 3, d0 = (tx & 7) * 8;   // sample 0..31, 8 dims
        const float* gp = xin + (size_t)(S0 + s) * D + d0;
        float4 a = ((const float4*)gp)[0];
        float4 b = ((const float4*)gp)[1];
        float vv[8] = {a.x, a.y, a.z, a.w, b.x, b.y, b.z, b.w};
        bf16x8 hv, lv;
#pragma unroll
        for (int j = 0; j < 8; ++j) {
            unsigned short hb = bf16_rne(vv[j]);
            hv[j] = (short)hb;
            lv[j] = (short)bf16_rne(vv[j] - bf16f(hb));
        }
        *(bf16x8*)(xh + s*72 + d0) = hv;
        *(bf16x8*)(xl + s*72 + d0) = lv;
#pragma unroll
        for (int q = 0; q < 4; ++q) cn_lds[q*256 + tx] = cnorm[q*256 + tx];
    }
    __syncthreads();

    const int w = tx >> 6, l = tx & 63;
    const int quad = l >> 4, col = l & 15;
    const int sh = w & 1;        // sample half
    const int ch = w >> 1;       // code half

    // loop-invariant A fragments: local sample = sh*16 + col, dims quad*8..+8
    const int srow = sh*16 + col;
    bf16x8 ahi0 = *(const bf16x8*)(xh + srow*72 + quad*8);
    bf16x8 ahi1 = *(const bf16x8*)(xh + srow*72 + 32 + quad*8);
    bf16x8 alo0 = *(const bf16x8*)(xl + srow*72 + quad*8);
    bf16x8 alo1 = *(const bf16x8*)(xl + srow*72 + 32 + quad*8);

    float b1[4], b2[4]; int i1[4], i2[4];
#pragma unroll
    for (int r = 0; r < 4; ++r) { b1[r]=3.4e38f; b2[r]=3.4e38f; i1[r]=0; i2[r]=0; }

    // B frags: lane supplies code = ch*512 + kb*16 + col, dims quad*8+j
    const unsigned short* bh = mhi + (size_t)(ch*512 + col)*D + quad*8;
    const unsigned short* bl = mlo + (size_t)(ch*512 + col)*D + quad*8;

    for (int kb = 0; kb < 32; ++kb) {
        bf16x8 bh0 = *(const bf16x8*)(bh);
        bf16x8 bh1 = *(const bf16x8*)(bh + 32);
        bf16x8 bl0 = *(const bf16x8*)(bl);
        bf16x8 bl1 = *(const bf16x8*)(bl + 32);
        f32x4 z = {0.f, 0.f, 0.f, 0.f};
        f32x4 hh = __builtin_amdgcn_mfma_f32_16x16x32_bf16(ahi0, bh0, z, 0,0,0);
        hh       = __builtin_amdgcn_mfma_f32_16x16x32_bf16(ahi1, bh1, hh, 0,0,0);
        f32x4 hl = __builtin_amdgcn_mfma_f32_16x16x32_bf16(ahi0, bl0, z, 0,0,0);
        hl       = __builtin_amdgcn_mfma_f32_16x16x32_bf16(ahi1, bl1, hl, 0,0,0);
        f32x4 lh = __builtin_amdgcn_mfma_f32_16x16x32_bf16(alo0, bh0, z, 0,0,0);
        lh       = __builtin_amdgcn_mfma_f32_16x16x32_bf16(alo1, bh1, lh, 0,0,0);
        const int kcode = ch*512 + kb*16 + col;
        const float cn = cn_lds[kcode];
#pragma unroll
        for (int r = 0; r < 4; ++r) {
            float dot = (hh[r] + hl[r]) + lh[r];
            float d = fmaf(-2.f, dot, cn);
            bool c1 = d < b1[r];
            bool c2 = d < b2[r];
            b2[r] = c1 ? b1[r] : (c2 ? d : b2[r]);
            i2[r] = c1 ? i1[r] : (c2 ? kcode : i2[r]);
            b1[r] = c1 ? d : b1[r];
            i1[r] = c1 ? kcode : i1[r];
        }
        bh += 16*D;
        bl += 16*D;
    }

    // ---- merge per-lane top-2 across 16 lanes x 2 code-halves ----
    __syncthreads();   // xh/xl dead (frags in regs) before alias overwrite
#pragma unroll
    for (int r = 0; r < 4; ++r) {
        mb1[tx*4 + r] = b1[r];
        mb2[tx*4 + r] = b2[r];
        mi1[tx*4 + r] = (short)i1[r];
        mi2[tx*4 + r] = (short)i2[r];
    }
    __syncthreads();

    if (tx < 32) {   // thread tx owns local sample tx
        const int msh = tx >> 4, mq = (tx >> 2) & 3, mr = tx & 3;
        float B1 = 3.4e38f, B2 = 3.4e38f; int I1 = 0, I2 = 0;
#pragma unroll
        for (int mch = 0; mch < 2; ++mch) {
            const int mw = mch*2 + msh;
#pragma unroll
            for (int c = 0; c < 16; ++c) {
                const int e = (mw*64 + mq*16 + c)*4 + mr;
                float v1 = mb1[e]; int j1 = mi1[e];
                float v2 = mb2[e]; int j2 = mi2[e];
                if (v1 < B1)      { B2 = B1; I2 = I1; B1 = v1; I1 = j1; }
                else if (v1 < B2) { B2 = v1; I2 = j1; }
                if (v2 < B1)      { B2 = B1; I2 = I1; B1 = v2; I1 = j2; }
                else if (v2 < B2) { B2 = v2; I2 = j2; }
            }
        }
        int winner = I1;
        if (B2 - B1 < MARGIN) {
            // exact fp32 rescore of both candidates from original cm
            const float* xp = xin + (size_t)(S0 + tx) * D;
            float a0=0,a1=0,a2=0,a3=0, e0=0,e1=0,e2=0,e3=0;
            for (int dd = 0; dd < D; dd += 4) {
                float x0 = xp[dd], x1 = xp[dd+1], x2 = xp[dd+2], x3 = xp[dd+3];
                a0 = fmaf(x0, cm[(dd+0)*K + I1], a0);
                a1 = fmaf(x1, cm[(dd+1)*K + I1], a1);
                a2 = fmaf(x2, cm[(dd+2)*K + I1], a2);
                a3 = fmaf(x3, cm[(dd+3)*K + I1], a3);
                e0 = fmaf(x0, cm[(dd+0)*K + I2], e0);
                e1 = fmaf(x1, cm[(dd+1)*K + I2], e1);
                e2 = fmaf(x2, cm[(dd+2)*K + I2], e2);
                e3 = fmaf(x3, cm[(dd+3)*K + I2], e3);
            }
            float d1 = fmaf(-2.f, (a0+a1)+(a2+a3), cn_lds[I1]);
            float d2 = fmaf(-2.f, (e0+e1)+(e2+e3), cn_lds[I2]);
            if (d2 < d1 || (d2 == d1 && I2 < I1)) winner = I2;
        }
        widx[tx] = winner;
    }
    __syncthreads();

    // ---- gather (hi+lo reconstruct, coalesced) + STE + loss partial ----
    const int sl = tx >> 3, d0 = (tx & 7) * 8;
    const int gs = S0 + sl;
    const int wi = widx[sl];
    bf16x8 h0 = *(const bf16x8*)(mhi + (size_t)wi*D + d0);
    bf16x8 l0 = *(const bf16x8*)(mlo + (size_t)wi*D + d0);
    const float* xr = xin + (size_t)gs*D + d0;
    float* oq = outq + (size_t)gs*D + d0;
    float psum = 0.f;
#pragma unroll
    for (int g = 0; g < 2; ++g) {
        float4 xv = *(const float4*)(xr + 4*g);
        float q0 = bf16f((unsigned short)h0[4*g+0]) + bf16f((unsigned short)l0[4*g+0]);
        float q1 = bf16f((unsigned short)h0[4*g+1]) + bf16f((unsigned short)l0[4*g+1]);
        float q2 = bf16f((unsigned short)h0[4*g+2]) + bf16f((unsigned short)l0[4*g+2]);
        float q3 = bf16f((unsigned short)h0[4*g+3]) + bf16f((unsigned short)l0[4*g+3]);
        float dx = q0 - xv.x, dy = q1 - xv.y, dz = q2 - xv.z, dw = q3 - xv.w;
        float4 o;
        o.x = xv.x + dx; o.y = xv.y + dy; o.z = xv.z + dz; o.w = xv.w + dw;
        *(float4*)(oq + 4*g) = o;
        psum = fmaf(dx, dx, psum);
        psum = fmaf(dy, dy, psum);
        psum = fmaf(dz, dz, psum);
        psum = fmaf(dw, dw, psum);
    }

    if (tx < 32)
        outidx[S0 + tx] = (float)widx[tx];

    red[tx] = psum;
    __syncthreads();
    for (int st = 128; st > 0; st >>= 1) {
        if (tx < st) red[tx] += red[tx + st];
        __syncthreads();
    }
    if (tx == 0) atomicAdd(acc_g, (double)red[0]);
}

// ---------------------------------------------------------------------------
// Finalize: loss = m + 0.25*m where m = mean((q-x)^2)
// ---------------------------------------------------------------------------
__global__ void vq_finalize(const double* __restrict__ acc,
                            float* __restrict__ loss_out)
{
    float m = (float)(*acc / (double)NEL);
    *loss_out = m + 0.25f * m;
}

extern "C" void kernel_launch(void* const* d_in, const int* in_sizes, int n_in,
                              void* d_out, int out_size, void* d_ws, size_t ws_size,
                              hipStream_t stream) {
    const float* xin = (const float*)d_in[0];   // [16,64,64,64] fp32
    const float* cm  = (const float*)d_in[1];   // [64,1024] fp32

    float* out     = (float*)d_out;
    float* outq    = out;                 // 4194304 floats
    float* outidx  = out + NEL;           // 65536 floats (indices)
    float* outloss = out + NEL + NS;      // 1 float

    // workspace: mhi 128 KB | mlo 128 KB | cnorm 4 KB | acc 8 B
    unsigned short* mhi = (unsigned short*)d_ws;
    unsigned short* mlo = mhi + (size_t)K * D;
    float*  cnorm = (float*)((char*)d_ws + 262144);
    double* acc   = (double*)((char*)d_ws + 266240);

    vq_prep<<<16, 256, 0, stream>>>(cm, mhi, mlo, cnorm, acc);
    vq_main<<<2048, 256, 0, stream>>>(xin, cm, mhi, mlo, cnorm, outq, outidx, acc);
    vq_finalize<<<1, 1, 0, stream>>>(acc, outloss);
}

// Round 13
// 134.038 us; speedup vs baseline: 1.9242x; 1.7647x over previous
//
#include <hip/hip_runtime.h>
#include <stdint.h>

#define NS 65536      // B*H*W samples
#define D 64          // embed dim
#define K 1024        // codebook size
#define NEL 4194304   // NS*D
#define MARGIN 0.05f  // approx-dist uncertainty margin (>> 2*eps ~ 1.4e-3)

typedef short bf16x8 __attribute__((ext_vector_type(8)));
typedef float f32x4 __attribute__((ext_vector_type(4)));

static __device__ __forceinline__ unsigned short bf16_rne(float x) {
    union { float f; uint32_t u; } v; v.f = x;
    uint32_t r = v.u + 0x7FFFu + ((v.u >> 16) & 1u);
    return (unsigned short)(r >> 16);
}
static __device__ __forceinline__ float bf16f(unsigned short h) {
    union { uint32_t u; float f; } v; v.u = ((uint32_t)h) << 16;
    return v.f;
}

// ---------------------------------------------------------------------------
// Prep: split codebook into bf16 hi/lo [K][D] row-major (MFMA-B-ready),
// compute ||m_k||^2 in fp32, zero the loss accumulator.
// ---------------------------------------------------------------------------
__global__ __launch_bounds__(256) void vq_prep(
    const float* __restrict__ cm,        // [D,K]
    unsigned short* __restrict__ mhi,    // [K,D] bf16 bits
    unsigned short* __restrict__ mlo,    // [K,D] bf16 bits
    float* __restrict__ cnorm,           // [K]
    double* __restrict__ acc)
{
    const int tx = threadIdx.x;
    const int kl = tx & 63, dq = tx >> 6;
    const int k = blockIdx.x * 64 + kl;
    if (blockIdx.x == 0 && tx == 0) *acc = 0.0;

    unsigned short h[16], lo[16];
    float p = 0.f;
#pragma unroll
    for (int j = 0; j < 16; ++j) {
        float v = cm[(dq*16 + j) * K + k];   // coalesced across k
        unsigned short hb = bf16_rne(v);
        h[j] = hb;
        lo[j] = bf16_rne(v - bf16f(hb));
        p = fmaf(v, v, p);
    }
    bf16x8 v0, v1, w0, w1;
#pragma unroll
    for (int j = 0; j < 8; ++j) {
        v0[j] = (short)h[j];  v1[j] = (short)h[8+j];
        w0[j] = (short)lo[j]; w1[j] = (short)lo[8+j];
    }
    *(bf16x8*)(mhi + (size_t)k*D + dq*16)     = v0;
    *(bf16x8*)(mhi + (size_t)k*D + dq*16 + 8) = v1;
    *(bf16x8*)(mlo + (size_t)k*D + dq*16)     = w0;
    *(bf16x8*)(mlo + (size_t)k*D + dq*16 + 8) = w1;

    __shared__ float pn[4][64];
    pn[dq][kl] = p;
    __syncthreads();
    if (tx < 64)
        cnorm[blockIdx.x*64 + tx] = (pn[0][tx]+pn[1][tx]) + (pn[2][tx]+pn[3][tx]);
}

// ---------------------------------------------------------------------------
// Main: MFMA bf16-split distance GEMM with LDS-staged double-buffered B.
// 1024 blocks x 256 thr (4 waves). Wave w handles samples w*16..+16, ALL
// 1024 codes in 64 tiles of 16. Per tile the 4 waves cooperatively stage
// 4 KB (hi/lo x chunk-half) via global_load_lds width=16 into btile[t&1],
// prefetched one tile ahead (m97 structure): barrier -> issue t+1 -> compute
// t. Staging lane = (chunk q = l>>4, code c = l&15) so compute ds_read_b128
// is base + lane*16 (conflict-free). B L2 traffic /4 vs R9 (shared).
// dot = x_hi.m_hi + x_hi.m_lo + x_lo.m_hi; per-lane top-2; LDS merge;
// margin cases rescored exactly in fp32 from original cm.
// ---------------------------------------------------------------------------
__global__ __launch_bounds__(256, 4) void vq_main(
    const float* __restrict__ xin,           // [NS,D]
    const float* __restrict__ cm,            // [D,K] (exact rescore)
    const unsigned short* __restrict__ mhi,  // [K,D]
    const unsigned short* __restrict__ mlo,  // [K,D]
    const float* __restrict__ cnorm,         // [K]
    float* __restrict__ outq,                // [NS,D]
    float* __restrict__ outidx,              // [NS]
    double* __restrict__ acc_g)
{
    // smemA phase1: xh[64][72] + xl[64][72] (18432 B)
    // smemA phase2 (alias): mb1/mb2 f32[1024] + mi1/mi2 i32[1024] (16 KB)
    // smemA phase3 (alias): red f32[256]
    __shared__ char smemA[18432];
    __shared__ unsigned short btile[2][2048];   // 2 x 4 KB B tiles
    __shared__ float cn_lds[1024];
    __shared__ int   widx[64];

    unsigned short* xh = (unsigned short*)smemA;           // stride 72
    unsigned short* xl = (unsigned short*)(smemA + 9216);
    float* mb1 = (float*)smemA;
    float* mb2 = (float*)(smemA + 4096);
    int*   mi1 = (int*)(smemA + 8192);
    int*   mi2 = (int*)(smemA + 12288);
    float* red = (float*)smemA;

    const int tx = threadIdx.x;
    const int S0 = blockIdx.x * 64;
    const int w = tx >> 6, l = tx & 63;
    const int quad = l >> 4, col = l & 15;

    // wave's staging role: source (hi/lo) x chunk-half; lane -> (code col,
    // chunk qh) so that LDS slot lane*16 == what compute-lane lane reads.
    const unsigned short* stage_src = (w & 2) ? mlo : mhi;
    const int qh = ((w & 1) << 2) + quad;          // chunk 0..7 (8 dims each)
    const unsigned short* stage_gp0 = stage_src + (size_t)col*D + qh*8;

    // ---- prefetch tile 0 (overlaps x staging below) ----
    __builtin_amdgcn_global_load_lds(stage_gp0, &btile[0][w*512], 16, 0, 0);

    // ---- stage x -> bf16 hi/lo in LDS ----
    {
        const int s = tx >> 2, d0 = (tx & 3) * 16;
        const float* gp = xin + (size_t)(S0 + s) * D + d0;
        bf16x8 hv0, hv1, lv0, lv1;
#pragma unroll
        for (int j = 0; j < 8; ++j) {
            float va = gp[j], vb = gp[8 + j];
            unsigned short ha = bf16_rne(va), hb = bf16_rne(vb);
            hv0[j] = (short)ha; hv1[j] = (short)hb;
            lv0[j] = (short)bf16_rne(va - bf16f(ha));
            lv1[j] = (short)bf16_rne(vb - bf16f(hb));
        }
        *(bf16x8*)(xh + s*72 + d0)     = hv0;
        *(bf16x8*)(xh + s*72 + d0 + 8) = hv1;
        *(bf16x8*)(xl + s*72 + d0)     = lv0;
        *(bf16x8*)(xl + s*72 + d0 + 8) = lv1;
#pragma unroll
        for (int q = 0; q < 4; ++q) cn_lds[q*256 + tx] = cnorm[q*256 + tx];
    }
    __syncthreads();   // drains x ds_writes AND tile-0 global_load_lds

    // loop-invariant A fragments: sample = w*16 + col, dims quad*8 (+32)
    const int srow = w*16 + col;
    bf16x8 ahi0 = *(const bf16x8*)(xh + srow*72 + quad*8);
    bf16x8 ahi1 = *(const bf16x8*)(xh + srow*72 + 32 + quad*8);
    bf16x8 alo0 = *(const bf16x8*)(xl + srow*72 + quad*8);
    bf16x8 alo1 = *(const bf16x8*)(xl + srow*72 + 32 + quad*8);

    float b1[4], b2[4]; int i1[4], i2[4];
#pragma unroll
    for (int r = 0; r < 4; ++r) { b1[r]=3.4e38f; b2[r]=3.4e38f; i1[r]=0; i2[r]=0; }

    for (int t = 0; t < 64; ++t) {
        if (t > 0) __syncthreads();   // tile t ready; buf (t+1)&1 free
        if (t < 63) {                 // prefetch t+1 (drained at next barrier)
            const unsigned short* gp = stage_gp0 + (size_t)(t+1)*16*D;
            __builtin_amdgcn_global_load_lds(gp, &btile[(t+1)&1][w*512], 16, 0, 0);
        }
        const unsigned short* bt = btile[t&1];
        bf16x8 bh0 = *(const bf16x8*)(bt + l*8);            // hi, chunks 0-3
        bf16x8 bh1 = *(const bf16x8*)(bt + 512  + l*8);     // hi, chunks 4-7
        bf16x8 bl0 = *(const bf16x8*)(bt + 1024 + l*8);     // lo, chunks 0-3
        bf16x8 bl1 = *(const bf16x8*)(bt + 1536 + l*8);     // lo, chunks 4-7
        f32x4 z = {0.f, 0.f, 0.f, 0.f};
        f32x4 hh = __builtin_amdgcn_mfma_f32_16x16x32_bf16(ahi0, bh0, z, 0,0,0);
        hh       = __builtin_amdgcn_mfma_f32_16x16x32_bf16(ahi1, bh1, hh, 0,0,0);
        f32x4 hl = __builtin_amdgcn_mfma_f32_16x16x32_bf16(ahi0, bl0, z, 0,0,0);
        hl       = __builtin_amdgcn_mfma_f32_16x16x32_bf16(ahi1, bl1, hl, 0,0,0);
        f32x4 lh = __builtin_amdgcn_mfma_f32_16x16x32_bf16(alo0, bh0, z, 0,0,0);
        lh       = __builtin_amdgcn_mfma_f32_16x16x32_bf16(alo1, bh1, lh, 0,0,0);
        const int kcode = t*16 + col;
        const float cn = cn_lds[kcode];
#pragma unroll
        for (int r = 0; r < 4; ++r) {
            float dot = (hh[r] + hl[r]) + lh[r];
            float d = fmaf(-2.f, dot, cn);
            bool c1 = d < b1[r];
            bool c2 = d < b2[r];
            b2[r] = c1 ? b1[r] : (c2 ? d : b2[r]);
            i2[r] = c1 ? i1[r] : (c2 ? kcode : i2[r]);
            b1[r] = c1 ? d : b1[r];
            i1[r] = c1 ? kcode : i1[r];
        }
        __syncthreads();  // all waves done reading bt before t+1 re-stage
    }

    // ---- merge per-lane top-2 across the 16 lanes per (wave,quad,reg) ----
#pragma unroll
    for (int r = 0; r < 4; ++r) {
        mb1[tx*4 + r] = b1[r];
        mb2[tx*4 + r] = b2[r];
        mi1[tx*4 + r] = i1[r];
        mi2[tx*4 + r] = i2[r];
    }
    __syncthreads();

    if (tx < 64) {   // thread tx owns local sample tx
        const int mw = tx >> 4, mq = (tx >> 2) & 3, mr = tx & 3;
        float B1 = 3.4e38f, B2 = 3.4e38f; int I1 = 0, I2 = 0;
#pragma unroll
        for (int c = 0; c < 16; ++c) {
            const int e = (mw*64 + mq*16 + c)*4 + mr;
            float v1 = mb1[e]; int j1 = mi1[e];
            float v2 = mb2[e]; int j2 = mi2[e];
            if (v1 < B1)      { B2 = B1; I2 = I1; B1 = v1; I1 = j1; }
            else if (v1 < B2) { B2 = v1; I2 = j1; }
            if (v2 < B1)      { B2 = B1; I2 = I1; B1 = v2; I1 = j2; }
            else if (v2 < B2) { B2 = v2; I2 = j2; }
        }
        int winner = I1;
        if (B2 - B1 < MARGIN) {
            // exact fp32 rescore of both candidates from original cm
            const float* xp = xin + (size_t)(S0 + tx) * D;
            float a0=0,a1=0,a2=0,a3=0, e0=0,e1=0,e2=0,e3=0;
            for (int dd = 0; dd < D; dd += 4) {
                float x0 = xp[dd], x1 = xp[dd+1], x2 = xp[dd+2], x3 = xp[dd+3];
                a0 = fmaf(x0, cm[(dd+0)*K + I1], a0);
                a1 = fmaf(x1, cm[(dd+1)*K + I1], a1);
                a2 = fmaf(x2, cm[(dd+2)*K + I1], a2);
                a3 = fmaf(x3, cm[(dd+3)*K + I1], a3);
                e0 = fmaf(x0, cm[(dd+0)*K + I2], e0);
                e1 = fmaf(x1, cm[(dd+1)*K + I2], e1);
                e2 = fmaf(x2, cm[(dd+2)*K + I2], e2);
                e3 = fmaf(x3, cm[(dd+3)*K + I2], e3);
            }
            float d1 = fmaf(-2.f, (a0+a1)+(a2+a3), cn_lds[I1]);
            float d2 = fmaf(-2.f, (e0+e1)+(e2+e3), cn_lds[I2]);
            if (d2 < d1 || (d2 == d1 && I2 < I1)) winner = I2;
        }
        widx[tx] = winner;
    }
    __syncthreads();

    // ---- gather (hi+lo reconstruct, coalesced) + STE + loss partial ----
    const int sl = tx >> 2, d0 = (tx & 3) * 16;
    const int gs = S0 + sl;
    const int wi = widx[sl];
    const unsigned short* mh = mhi + (size_t)wi*D + d0;
    const unsigned short* ml = mlo + (size_t)wi*D + d0;
    bf16x8 h0 = *(const bf16x8*)(mh);
    bf16x8 h1 = *(const bf16x8*)(mh + 8);
    bf16x8 l0 = *(const bf16x8*)(ml);
    bf16x8 l1 = *(const bf16x8*)(ml + 8);
    const float* xr = xin + (size_t)gs*D + d0;
    float* oq = outq + (size_t)gs*D + d0;
    float psum = 0.f;
#pragma unroll
    for (int g = 0; g < 4; ++g) {
        float4 xv = *(const float4*)(xr + 4*g);
        float q0 = bf16f((unsigned short)(g < 2 ? h0[4*g+0] : h1[4*g-8+0])) +
                   bf16f((unsigned short)(g < 2 ? l0[4*g+0] : l1[4*g-8+0]));
        float q1 = bf16f((unsigned short)(g < 2 ? h0[4*g+1] : h1[4*g-8+1])) +
                   bf16f((unsigned short)(g < 2 ? l0[4*g+1] : l1[4*g-8+1]));
        float q2 = bf16f((unsigned short)(g < 2 ? h0[4*g+2] : h1[4*g-8+2])) +
                   bf16f((unsigned short)(g < 2 ? l0[4*g+2] : l1[4*g-8+2]));
        float q3 = bf16f((unsigned short)(g < 2 ? h0[4*g+3] : h1[4*g-8+3])) +
                   bf16f((unsigned short)(g < 2 ? l0[4*g+3] : l1[4*g-8+3]));
        float dx = q0 - xv.x, dy = q1 - xv.y, dz = q2 - xv.z, dw = q3 - xv.w;
        float4 o;
        o.x = xv.x + dx; o.y = xv.y + dy; o.z = xv.z + dz; o.w = xv.w + dw;
        *(float4*)(oq + 4*g) = o;
        psum = fmaf(dx, dx, psum);
        psum = fmaf(dy, dy, psum);
        psum = fmaf(dz, dz, psum);
        psum = fmaf(dw, dw, psum);
    }

    if (tx < 64)
        outidx[S0 + tx] = (float)widx[tx];

    red[tx] = psum;
    __syncthreads();
    for (int st = 128; st > 0; st >>= 1) {
        if (tx < st) red[tx] += red[tx + st];
        __syncthreads();
    }
    if (tx == 0) atomicAdd(acc_g, (double)red[0]);
}

// ---------------------------------------------------------------------------
// Finalize: loss = m + 0.25*m where m = mean((q-x)^2)
// ---------------------------------------------------------------------------
__global__ void vq_finalize(const double* __restrict__ acc,
                            float* __restrict__ loss_out)
{
    float m = (float)(*acc / (double)NEL);
    *loss_out = m + 0.25f * m;
}

extern "C" void kernel_launch(void* const* d_in, const int* in_sizes, int n_in,
                              void* d_out, int out_size, void* d_ws, size_t ws_size,
                              hipStream_t stream) {
    const float* xin = (const float*)d_in[0];   // [16,64,64,64] fp32
    const float* cm  = (const float*)d_in[1];   // [64,1024] fp32

    float* out     = (float*)d_out;
    float* outq    = out;                 // 4194304 floats
    float* outidx  = out + NEL;           // 65536 floats (indices)
    float* outloss = out + NEL + NS;      // 1 float

    // workspace: mhi 128 KB | mlo 128 KB | cnorm 4 KB | acc 8 B
    unsigned short* mhi = (unsigned short*)d_ws;
    unsigned short* mlo = mhi + (size_t)K * D;
    float*  cnorm = (float*)((char*)d_ws + 262144);
    double* acc   = (double*)((char*)d_ws + 266240);

    vq_prep<<<16, 256, 0, stream>>>(cm, mhi, mlo, cnorm, acc);
    vq_main<<<1024, 256, 0, stream>>>(xin, cm, mhi, mlo, cnorm, outq, outidx, acc);
    vq_finalize<<<1, 1, 0, stream>>>(acc, outloss);
}